// Round 28
// baseline (320.915 us; speedup 1.0000x reference)
//
#include <hip/hip_runtime.h>

// ---------------- CSR build via 2-level bucket sort (r24, verified) ----------

#define EBLK 4096

__global__ __launch_bounds__(256) void bucket_hist_kernel(
    const int* __restrict__ ei, int* __restrict__ cnt, int E)
{
    __shared__ int h[256];
    int tid = threadIdx.x;
    h[tid] = 0;
    __syncthreads();
    int e0 = blockIdx.x * EBLK;
    int ecnt = min(EBLK, E - e0);
    for (int i = tid; i < ecnt; i += 256)
        atomicAdd(&h[ei[E + e0 + i] >> 9], 1);
    __syncthreads();
    if (h[tid]) atomicAdd(&cnt[tid], h[tid]);
}

__global__ __launch_bounds__(256) void bucket_scan_kernel(
    const int* __restrict__ cnt, int* __restrict__ bbase,
    int* __restrict__ bcur, int nb, int E)
{
    __shared__ int s[256];
    int t = threadIdx.x;
    s[t] = (t < nb) ? cnt[t] : 0;
    __syncthreads();
    for (int off = 1; off < 256; off <<= 1) {
        int v = 0;
        if (t >= off) v = s[t - off];
        __syncthreads();
        if (t >= off) s[t] += v;
        __syncthreads();
    }
    int ex = (t == 0) ? 0 : s[t - 1];
    if (t < nb) { bbase[t] = ex; bcur[t] = ex; }
    if (t == 0) bbase[nb] = E;
}

__global__ __launch_bounds__(256) void bin_scatter_kernel(
    const int* __restrict__ ei, int* __restrict__ bcur,
    uint2* __restrict__ ebuf, int E)
{
    __shared__ int h[256];
    __shared__ int start[256];
    int tid = threadIdx.x;
    int e0 = blockIdx.x * EBLK;
    int ecnt = min(EBLK, E - e0);
    h[tid] = 0;
    start[tid] = 0;
    __syncthreads();
    for (int i = tid; i < ecnt; i += 256)
        atomicAdd(&h[ei[E + e0 + i] >> 9], 1);
    __syncthreads();
    if (h[tid] > 0) start[tid] = atomicAdd(&bcur[tid], h[tid]);
    __syncthreads();
    h[tid] = start[tid];          // reuse h as running global cursor
    __syncthreads();
    for (int i = tid; i < ecnt; i += 256) {
        int src = ei[e0 + i];
        int dst = ei[E + e0 + i];
        int pos = atomicAdd(&h[dst >> 9], 1);
        ebuf[pos] = make_uint2((unsigned)src, (unsigned)dst);
    }
}

__global__ __launch_bounds__(512) void bucket_fill_kernel(
    const uint2* __restrict__ ebuf, const int* __restrict__ bbase,
    int* __restrict__ offs, float* __restrict__ invd,
    int* __restrict__ csr, int N, int E)
{
    __shared__ int deg[512];
    __shared__ int s[512];
    int b = blockIdx.x;
    int lo = b << 9;
    int base = bbase[b];
    int end = bbase[b + 1];
    int tid = threadIdx.x;
    deg[tid] = 0;
    __syncthreads();
    for (int i = base + tid; i < end; i += 512)
        atomicAdd(&deg[(int)ebuf[i].y - lo], 1);
    __syncthreads();
    int d = deg[tid];
    s[tid] = d;
    __syncthreads();
    for (int off = 1; off < 512; off <<= 1) {
        int v = 0;
        if (tid >= off) v = s[tid - off];
        __syncthreads();
        if (tid >= off) s[tid] += v;
        __syncthreads();
    }
    int ex = s[tid] - d;          // exclusive prefix within bucket
    int n = lo + tid;
    if (n < N) {
        offs[n] = base + ex;
        invd[n] = 1.0f / (float)(d > 0 ? d : 1);
    }
    __syncthreads();
    deg[tid] = ex;                // reuse deg as local cursor
    __syncthreads();
    for (int i = base + tid; i < end; i += 512) {
        uint2 ed = ebuf[i];
        int pos = atomicAdd(&deg[(int)ed.y - lo], 1);
        csr[base + pos] = (int)ed.x;
    }
    if (b == 0 && tid == 0) offs[N] = E;
}

// ---------------- bf16 helpers ----------------

__device__ inline unsigned short f2bf(float f) {
    unsigned int u = __float_as_uint(f);
    return (unsigned short)((u + 0x7fffu + ((u >> 16) & 1u)) >> 16);
}

__device__ inline float bflo(unsigned int u) { return __uint_as_float(u << 16); }
__device__ inline float bfhi(unsigned int u) { return __uint_as_float(u & 0xffff0000u); }

__global__ void f32_to_bf16_kernel(const float* __restrict__ in,
                                   unsigned short* __restrict__ out, int n4) {
    int i = blockIdx.x * blockDim.x + threadIdx.x;
    if (i < n4) {
        float4 v = *(const float4*)(in + (size_t)i * 4);
        ushort4 o;
        o.x = f2bf(v.x); o.y = f2bf(v.y); o.z = f2bf(v.z); o.w = f2bf(v.w);
        *(ushort4*)(out + (size_t)i * 4) = o;
    }
}

// ---------------- mean aggregation (2-chain; optional column slicing) --------
// Round-28: layer-1 gather split into 2 column-half passes (working set
// 25.6MB -> 12.8MB per pass) to raise per-XCD L2 hit rate; FETCH was 7x the
// source size (180MB/dispatch).

__device__ inline void addbf8(float* a, uint4 v) {
    a[0] += bflo(v.x); a[1] += bfhi(v.x);
    a[2] += bflo(v.y); a[3] += bfhi(v.y);
    a[4] += bflo(v.z); a[5] += bfhi(v.z);
    a[6] += bflo(v.w); a[7] += bfhi(v.w);
}

// D = active columns this pass; LD = row stride (elements); coloff = start col
template <int D, int LD>
__global__ __launch_bounds__(256) void aggregate_bf16_kernel(
    const unsigned short* __restrict__ hb, const int* __restrict__ offs,
    const int* __restrict__ csr, const float* __restrict__ invd,
    unsigned short* __restrict__ meanb, int coloff, int nN)
{
    constexpr int LPR = D / 8;
    constexpr int G = 64 / LPR;
    int wid = blockIdx.x * 4 + (threadIdx.x >> 6);
    int lane = threadIdx.x & 63;
    if (wid >= nN) return;
    int o0 = offs[wid], o1 = offs[wid + 1];
    const int p = lane / LPR;
    const int col = coloff + (lane % LPR) * 8;

    float a0[8] = {0.f, 0.f, 0.f, 0.f, 0.f, 0.f, 0.f, 0.f};
    float a1[8] = {0.f, 0.f, 0.f, 0.f, 0.f, 0.f, 0.f, 0.f};
    int j = o0;
    for (; j + 2 * G <= o1; j += 2 * G) {
        int s0 = csr[j + p];
        int s1 = csr[j + G + p];
        uint4 v0 = *(const uint4*)(hb + (size_t)s0 * LD + col);
        uint4 v1 = *(const uint4*)(hb + (size_t)s1 * LD + col);
        addbf8(a0, v0);
        addbf8(a1, v1);
    }
    if (j + G <= o1) {
        int s0 = csr[j + p];
        uint4 v0 = *(const uint4*)(hb + (size_t)s0 * LD + col);
        addbf8(a0, v0);
        j += G;
    }
    if (j < o1 && p < o1 - j) {
        int s1 = csr[j + p];
        uint4 v1 = *(const uint4*)(hb + (size_t)s1 * LD + col);
        addbf8(a1, v1);
    }
#pragma unroll
    for (int q = 0; q < 8; q++) a0[q] += a1[q];

#pragma unroll
    for (int m = LPR; m < 64; m <<= 1) {
#pragma unroll
        for (int q = 0; q < 8; q++) a0[q] += __shfl_xor(a0[q], m);
    }

    if (lane < LPR) {
        float iv = invd[wid];
        uint4 o;
        o.x = (unsigned)f2bf(a0[0] * iv) | ((unsigned)f2bf(a0[1] * iv) << 16);
        o.y = (unsigned)f2bf(a0[2] * iv) | ((unsigned)f2bf(a0[3] * iv) << 16);
        o.z = (unsigned)f2bf(a0[4] * iv) | ((unsigned)f2bf(a0[5] * iv) << 16);
        o.w = (unsigned)f2bf(a0[6] * iv) | ((unsigned)f2bf(a0[7] * iv) << 16);
        *(uint4*)(meanb + (size_t)wid * LD + col) = o;
    }
}

// ---------------- aggregate + finish: out = relu(mean_agg(p) + bias + q) -----

template <int D, bool F32OUT>
__global__ __launch_bounds__(256) void agg_finish_kernel(
    const unsigned short* __restrict__ pb, const unsigned short* __restrict__ qb,
    const float* __restrict__ bias, const int* __restrict__ offs,
    const int* __restrict__ csr, const float* __restrict__ invd,
    unsigned short* __restrict__ outb, float* __restrict__ outf, int nN)
{
    constexpr int LPR = D / 8;
    constexpr int G = 64 / LPR;
    int wid = blockIdx.x * 4 + (threadIdx.x >> 6);
    int lane = threadIdx.x & 63;
    if (wid >= nN) return;
    int o0 = offs[wid], o1 = offs[wid + 1];
    const int p = lane / LPR;
    const int col = (lane % LPR) * 8;

    float a0[8] = {0.f, 0.f, 0.f, 0.f, 0.f, 0.f, 0.f, 0.f};
    float a1[8] = {0.f, 0.f, 0.f, 0.f, 0.f, 0.f, 0.f, 0.f};
    int j = o0;
    for (; j + 2 * G <= o1; j += 2 * G) {
        int s0 = csr[j + p];
        int s1 = csr[j + G + p];
        uint4 v0 = *(const uint4*)(pb + (size_t)s0 * D + col);
        uint4 v1 = *(const uint4*)(pb + (size_t)s1 * D + col);
        addbf8(a0, v0);
        addbf8(a1, v1);
    }
    if (j + G <= o1) {
        int s0 = csr[j + p];
        uint4 v0 = *(const uint4*)(pb + (size_t)s0 * D + col);
        addbf8(a0, v0);
        j += G;
    }
    if (j < o1 && p < o1 - j) {
        int s1 = csr[j + p];
        uint4 v1 = *(const uint4*)(pb + (size_t)s1 * D + col);
        addbf8(a1, v1);
    }
#pragma unroll
    for (int q = 0; q < 8; q++) a0[q] += a1[q];

#pragma unroll
    for (int m = LPR; m < 64; m <<= 1) {
#pragma unroll
        for (int q = 0; q < 8; q++) a0[q] += __shfl_xor(a0[q], m);
    }

    if (lane < LPR) {
        float iv = invd[wid];
        uint4 qv = *(const uint4*)(qb + (size_t)wid * D + col);
        float qf[8];
        qf[0] = bflo(qv.x); qf[1] = bfhi(qv.x);
        qf[2] = bflo(qv.y); qf[3] = bfhi(qv.y);
        qf[4] = bflo(qv.z); qf[5] = bfhi(qv.z);
        qf[6] = bflo(qv.w); qf[7] = bfhi(qv.w);
        float r[8];
#pragma unroll
        for (int q = 0; q < 8; q++)
            r[q] = fmaxf(a0[q] * iv + qf[q] + bias[col + q], 0.f);
        if (F32OUT) {
            float* dst = outf + (size_t)wid * D + col;
            *(float4*)(dst)     = make_float4(r[0], r[1], r[2], r[3]);
            *(float4*)(dst + 4) = make_float4(r[4], r[5], r[6], r[7]);
        } else {
            uint4 o;
            o.x = (unsigned)f2bf(r[0]) | ((unsigned)f2bf(r[1]) << 16);
            o.y = (unsigned)f2bf(r[2]) | ((unsigned)f2bf(r[3]) << 16);
            o.z = (unsigned)f2bf(r[4]) | ((unsigned)f2bf(r[5]) << 16);
            o.w = (unsigned)f2bf(r[6]) | ((unsigned)f2bf(r[7]) << 16);
            *(uint4*)(outb + (size_t)wid * D + col) = o;
        }
    }
}

// ---------------- MFMA GEMMs (layouts verified r22, absmax 1.95e-3) ----------

typedef short short8 __attribute__((ext_vector_type(8)));
typedef short short4v __attribute__((ext_vector_type(4)));
typedef float f32x4 __attribute__((ext_vector_type(4)));

__global__ void swizzle_w_kernel(const float* __restrict__ W,
                                 unsigned short* __restrict__ Ws,
                                 int K, int M) {
    int t = blockIdx.x * blockDim.x + threadIdx.x;
    int KB = K >> 5;
    int total = (M >> 4) * KB * 64;
    if (t >= total) return;
    int l = t & 63;
    int kbc = t >> 6;
    int kb = kbc % KB;
    int c = kbc / KB;
    int km = kb * 32 + ((l >> 4) << 2);
    int m = (c << 4) + (l & 15);
    unsigned short o[8];
#pragma unroll
    for (int j = 0; j < 8; j++) {
        int k = km + (j >> 2) * 16 + (j & 3);
        o[j] = f2bf(W[(size_t)k * M + m]);
    }
    *(uint4*)(Ws + (size_t)t * 8) = *(uint4*)o;
}

// dual-input fused GEMM (layer 1): out = relu(A1@w1 + A2@w2 + bias)
template <int K, int M>
__global__ __launch_bounds__(512) void gemm_mfma(
    const unsigned short* __restrict__ A1, const unsigned short* __restrict__ A2,
    const unsigned short* __restrict__ w1s, const unsigned short* __restrict__ w2s,
    const float* __restrict__ bias, float* __restrict__ out,
    unsigned short* __restrict__ outb, int nN)
{
    constexpr int KB = K / 32;
    constexpr int CB = M / 16;
    const int l = threadIdx.x & 63;
    const int wv = threadIdx.x >> 6;
    const int rowbase = blockIdx.x * 128 + wv * 16;
    if (rowbase >= nN) return;
    const int arow = rowbase + (l & 15);
    const int ksub = (l >> 4) << 2;

    f32x4 acc[CB];
#pragma unroll
    for (int c = 0; c < CB; c++) acc[c] = (f32x4){0.f, 0.f, 0.f, 0.f};

    const unsigned short* a1p = A1 + (size_t)arow * K + ksub;
    const unsigned short* a2p = A2 + (size_t)arow * K + ksub;

#pragma unroll
    for (int kb = 0; kb < KB; kb++) {
        short4v l1 = *(const short4v*)(a1p + kb * 32);
        short4v h1 = *(const short4v*)(a1p + kb * 32 + 16);
        short4v l2 = *(const short4v*)(a2p + kb * 32);
        short4v h2 = *(const short4v*)(a2p + kb * 32 + 16);
        short8 a1 = {l1[0], l1[1], l1[2], l1[3], h1[0], h1[1], h1[2], h1[3]};
        short8 a2 = {l2[0], l2[1], l2[2], l2[3], h2[0], h2[1], h2[2], h2[3]};
#pragma unroll
        for (int c = 0; c < CB; c++) {
            short8 b1 = *(const short8*)(w1s + ((size_t)(c * KB + kb) * 64 + l) * 8);
            acc[c] = __builtin_amdgcn_mfma_f32_16x16x32_bf16(a1, b1, acc[c], 0, 0, 0);
            short8 b2 = *(const short8*)(w2s + ((size_t)(c * KB + kb) * 64 + l) * 8);
            acc[c] = __builtin_amdgcn_mfma_f32_16x16x32_bf16(a2, b2, acc[c], 0, 0, 0);
        }
    }

    const int orow = rowbase + ((l >> 4) << 2);
#pragma unroll
    for (int c = 0; c < CB; c++) {
        int col = (c << 4) + (l & 15);
        float bv = bias[col];
#pragma unroll
        for (int r = 0; r < 4; r++) {
            float v = fmaxf(acc[c][r] + bv, 0.f);
            size_t idx = (size_t)(orow + r) * M + col;
            if (out) out[idx] = v;
            if (outb) outb[idx] = f2bf(v);
        }
    }
}

// split-output GEMM (layers 2-3): pb = A@w1 (raw), qb = A@w2 (raw); one A stream
template <int K, int M>
__global__ __launch_bounds__(512) void gemm_mfma_split(
    const unsigned short* __restrict__ A,
    const unsigned short* __restrict__ w1s, const unsigned short* __restrict__ w2s,
    unsigned short* __restrict__ pb, unsigned short* __restrict__ qb, int nN)
{
    constexpr int KB = K / 32;
    constexpr int CB = M / 16;
    const int l = threadIdx.x & 63;
    const int wv = threadIdx.x >> 6;
    const int rowbase = blockIdx.x * 128 + wv * 16;
    if (rowbase >= nN) return;
    const int arow = rowbase + (l & 15);
    const int ksub = (l >> 4) << 2;

    f32x4 accp[CB], accq[CB];
#pragma unroll
    for (int c = 0; c < CB; c++) {
        accp[c] = (f32x4){0.f, 0.f, 0.f, 0.f};
        accq[c] = (f32x4){0.f, 0.f, 0.f, 0.f};
    }

    const unsigned short* ap = A + (size_t)arow * K + ksub;

#pragma unroll
    for (int kb = 0; kb < KB; kb++) {
        short4v lo = *(const short4v*)(ap + kb * 32);
        short4v hi = *(const short4v*)(ap + kb * 32 + 16);
        short8 a = {lo[0], lo[1], lo[2], lo[3], hi[0], hi[1], hi[2], hi[3]};
#pragma unroll
        for (int c = 0; c < CB; c++) {
            short8 b1 = *(const short8*)(w1s + ((size_t)(c * KB + kb) * 64 + l) * 8);
            accp[c] = __builtin_amdgcn_mfma_f32_16x16x32_bf16(a, b1, accp[c], 0, 0, 0);
            short8 b2 = *(const short8*)(w2s + ((size_t)(c * KB + kb) * 64 + l) * 8);
            accq[c] = __builtin_amdgcn_mfma_f32_16x16x32_bf16(a, b2, accq[c], 0, 0, 0);
        }
    }

    const int orow = rowbase + ((l >> 4) << 2);
#pragma unroll
    for (int c = 0; c < CB; c++) {
        int col = (c << 4) + (l & 15);
#pragma unroll
        for (int r = 0; r < 4; r++) {
            size_t idx = (size_t)(orow + r) * M + col;
            pb[idx] = f2bf(accp[c][r]);
            qb[idx] = f2bf(accq[c][r]);
        }
    }
}

// ---------------- classifier: [N,32] @ [32,2] + bc ----------------

__global__ void classifier_kernel(const float* __restrict__ h,
                                  const float* __restrict__ wc,
                                  const float* __restrict__ bc,
                                  float* __restrict__ out, int nN) {
    int n = blockIdx.x * blockDim.x + threadIdx.x;
    if (n >= nN) return;
    float a0 = bc[0], a1 = bc[1];
    const float* row = h + (size_t)n * 32;
#pragma unroll
    for (int k = 0; k < 32; k++) {
        float v = row[k];
        a0 = fmaf(v, wc[k * 2 + 0], a0);
        a1 = fmaf(v, wc[k * 2 + 1], a1);
    }
    out[n * 2 + 0] = a0;
    out[n * 2 + 1] = a1;
}

// ---------------- launch ----------------

extern "C" void kernel_launch(void* const* d_in, const int* in_sizes, int n_in,
                              void* d_out, int out_size, void* d_ws, size_t ws_size,
                              hipStream_t stream) {
    const float* x   = (const float*)d_in[0];
    const int*   ei  = (const int*)d_in[1];   // [2,E] int32
    const float* w1l = (const float*)d_in[2];
    const float* b1l = (const float*)d_in[3];
    const float* w1r = (const float*)d_in[4];
    const float* w2l = (const float*)d_in[5];
    const float* b2l = (const float*)d_in[6];
    const float* w2r = (const float*)d_in[7];
    const float* w3l = (const float*)d_in[8];
    const float* b3l = (const float*)d_in[9];
    const float* w3r = (const float*)d_in[10];
    const float* wc  = (const float*)d_in[11];
    const float* bc  = (const float*)d_in[12];
    float* out = (float*)d_out;

    const int N = in_sizes[0] / 128;
    const int E = in_sizes[1] / 2;
    const int NBq = (N + 511) >> 9;           // 512-node buckets (196)

    char* p = (char*)d_ws;
    auto alloc = [&](size_t bytes) {
        char* r = p;
        p += (bytes + 511) & ~(size_t)511;
        return r;
    };
    int*   offs   = (int*)  alloc(((size_t)N + 1) * 4);
    float* invd   = (float*)alloc((size_t)N * 4);
    int*   bcnt   = (int*)  alloc(256 * 4);
    int*   bbase  = (int*)  alloc(257 * 4);
    int*   bcur   = (int*)  alloc(256 * 4);
    uint2* ebuf   = (uint2*)alloc((size_t)E * 8);
    int*   csr    = (int*)  alloc((size_t)E * 4);
    float* h3     = (float*)alloc((size_t)N * 32 * 4);
    unsigned short* xb    = (unsigned short*)alloc((size_t)N * 128 * 2);
    unsigned short* h1b   = (unsigned short*)alloc((size_t)N * 128 * 2);
    unsigned short* h2b   = (unsigned short*)alloc((size_t)N * 64 * 2);
    unsigned short* meanb = (unsigned short*)alloc((size_t)N * 128 * 2);
    unsigned short* p2b   = (unsigned short*)alloc((size_t)N * 64 * 2);
    unsigned short* q2b   = (unsigned short*)alloc((size_t)N * 64 * 2);
    unsigned short* p3b   = (unsigned short*)alloc((size_t)N * 32 * 2);
    unsigned short* q3b   = (unsigned short*)alloc((size_t)N * 32 * 2);
    unsigned short* w1ls  = (unsigned short*)alloc(128 * 128 * 2);
    unsigned short* w1rs  = (unsigned short*)alloc(128 * 128 * 2);
    unsigned short* w2ls  = (unsigned short*)alloc(128 * 64 * 2);
    unsigned short* w2rs  = (unsigned short*)alloc(128 * 64 * 2);
    unsigned short* w3ls  = (unsigned short*)alloc(64 * 32 * 2);
    unsigned short* w3rs  = (unsigned short*)alloc(64 * 32 * 2);

    hipMemsetAsync(bcnt, 0, 256 * 4, stream);

    int eb4 = (E + EBLK - 1) / EBLK;
    bucket_hist_kernel<<<eb4, 256, 0, stream>>>(ei, bcnt, E);
    bucket_scan_kernel<<<1, 256, 0, stream>>>(bcnt, bbase, bcur, NBq, E);
    bin_scatter_kernel<<<eb4, 256, 0, stream>>>(ei, bcur, ebuf, E);
    bucket_fill_kernel<<<NBq, 512, 0, stream>>>(ebuf, bbase, offs, invd, csr, N, E);

    int n4 = N * 128 / 4;
    f32_to_bf16_kernel<<<(n4 + 255) / 256, 256, 0, stream>>>(x, xb, n4);

    // weight swizzle (tiny)
    swizzle_w_kernel<<<(128 * 128 / 8 + 255) / 256, 256, 0, stream>>>(w1l, w1ls, 128, 128);
    swizzle_w_kernel<<<(128 * 128 / 8 + 255) / 256, 256, 0, stream>>>(w1r, w1rs, 128, 128);
    swizzle_w_kernel<<<(128 * 64 / 8 + 255) / 256, 256, 0, stream>>>(w2l, w2ls, 128, 64);
    swizzle_w_kernel<<<(128 * 64 / 8 + 255) / 256, 256, 0, stream>>>(w2r, w2rs, 128, 64);
    swizzle_w_kernel<<<(64 * 32 / 8 + 255) / 256, 256, 0, stream>>>(w3l, w3ls, 64, 32);
    swizzle_w_kernel<<<(64 * 32 / 8 + 255) / 256, 256, 0, stream>>>(w3r, w3rs, 64, 32);

    int ab = (N + 3) / 4;
    int gm = (N + 127) / 128;     // 128 rows per MFMA block

    // layer 1: gather in two 64-column passes (smaller L2 working set)
    aggregate_bf16_kernel<64, 128><<<ab, 256, 0, stream>>>(xb, offs, csr, invd, meanb, 0, N);
    aggregate_bf16_kernel<64, 128><<<ab, 256, 0, stream>>>(xb, offs, csr, invd, meanb, 64, N);
    gemm_mfma<128, 128><<<gm, 512, 0, stream>>>(meanb, xb, w1ls, w1rs, b1l, nullptr, h1b, N);

    // layer 2 (aggregate AFTER lin_l: gather 64-wide instead of 128-wide)
    gemm_mfma_split<128, 64><<<gm, 512, 0, stream>>>(h1b, w2ls, w2rs, p2b, q2b, N);
    agg_finish_kernel<64, false><<<ab, 256, 0, stream>>>(p2b, q2b, b2l, offs, csr, invd, h2b, nullptr, N);

    // layer 3 (gather 32-wide instead of 64-wide)
    gemm_mfma_split<64, 32><<<gm, 512, 0, stream>>>(h2b, w3ls, w3rs, p3b, q3b, N);
    agg_finish_kernel<32, true><<<ab, 256, 0, stream>>>(p3b, q3b, b3l, offs, csr, invd, nullptr, h3, N);

    classifier_kernel<<<(N + 255) / 256, 256, 0, stream>>>(h3, wc, bc, out, N);
}

// Round 29
// 298.738 us; speedup vs baseline: 1.0742x; 1.0742x over previous
//
#include <hip/hip_runtime.h>

// ---------------- CSR build via 2-level bucket sort (r24, verified) ----------

#define EBLK 4096

__global__ __launch_bounds__(256) void bucket_hist_kernel(
    const int* __restrict__ ei, int* __restrict__ cnt, int E)
{
    __shared__ int h[256];
    int tid = threadIdx.x;
    h[tid] = 0;
    __syncthreads();
    int e0 = blockIdx.x * EBLK;
    int ecnt = min(EBLK, E - e0);
    for (int i = tid; i < ecnt; i += 256)
        atomicAdd(&h[ei[E + e0 + i] >> 9], 1);
    __syncthreads();
    if (h[tid]) atomicAdd(&cnt[tid], h[tid]);
}

__global__ __launch_bounds__(256) void bucket_scan_kernel(
    const int* __restrict__ cnt, int* __restrict__ bbase,
    int* __restrict__ bcur, int nb, int E)
{
    __shared__ int s[256];
    int t = threadIdx.x;
    s[t] = (t < nb) ? cnt[t] : 0;
    __syncthreads();
    for (int off = 1; off < 256; off <<= 1) {
        int v = 0;
        if (t >= off) v = s[t - off];
        __syncthreads();
        if (t >= off) s[t] += v;
        __syncthreads();
    }
    int ex = (t == 0) ? 0 : s[t - 1];
    if (t < nb) { bbase[t] = ex; bcur[t] = ex; }
    if (t == 0) bbase[nb] = E;
}

__global__ __launch_bounds__(256) void bin_scatter_kernel(
    const int* __restrict__ ei, int* __restrict__ bcur,
    uint2* __restrict__ ebuf, int E)
{
    __shared__ int h[256];
    __shared__ int start[256];
    int tid = threadIdx.x;
    int e0 = blockIdx.x * EBLK;
    int ecnt = min(EBLK, E - e0);
    h[tid] = 0;
    start[tid] = 0;
    __syncthreads();
    for (int i = tid; i < ecnt; i += 256)
        atomicAdd(&h[ei[E + e0 + i] >> 9], 1);
    __syncthreads();
    if (h[tid] > 0) start[tid] = atomicAdd(&bcur[tid], h[tid]);
    __syncthreads();
    h[tid] = start[tid];          // reuse h as running global cursor
    __syncthreads();
    for (int i = tid; i < ecnt; i += 256) {
        int src = ei[e0 + i];
        int dst = ei[E + e0 + i];
        int pos = atomicAdd(&h[dst >> 9], 1);
        ebuf[pos] = make_uint2((unsigned)src, (unsigned)dst);
    }
}

__global__ __launch_bounds__(512) void bucket_fill_kernel(
    const uint2* __restrict__ ebuf, const int* __restrict__ bbase,
    int* __restrict__ offs, float* __restrict__ invd,
    int* __restrict__ csr, int N, int E)
{
    __shared__ int deg[512];
    __shared__ int s[512];
    int b = blockIdx.x;
    int lo = b << 9;
    int base = bbase[b];
    int end = bbase[b + 1];
    int tid = threadIdx.x;
    deg[tid] = 0;
    __syncthreads();
    for (int i = base + tid; i < end; i += 512)
        atomicAdd(&deg[(int)ebuf[i].y - lo], 1);
    __syncthreads();
    int d = deg[tid];
    s[tid] = d;
    __syncthreads();
    for (int off = 1; off < 512; off <<= 1) {
        int v = 0;
        if (tid >= off) v = s[tid - off];
        __syncthreads();
        if (tid >= off) s[tid] += v;
        __syncthreads();
    }
    int ex = s[tid] - d;          // exclusive prefix within bucket
    int n = lo + tid;
    if (n < N) {
        offs[n] = base + ex;
        invd[n] = 1.0f / (float)(d > 0 ? d : 1);
    }
    __syncthreads();
    deg[tid] = ex;                // reuse deg as local cursor
    __syncthreads();
    for (int i = base + tid; i < end; i += 512) {
        uint2 ed = ebuf[i];
        int pos = atomicAdd(&deg[(int)ed.y - lo], 1);
        csr[base + pos] = (int)ed.x;
    }
    if (b == 0 && tid == 0) offs[N] = E;
}

// ---------------- bf16 helpers ----------------

__device__ inline unsigned short f2bf(float f) {
    unsigned int u = __float_as_uint(f);
    return (unsigned short)((u + 0x7fffu + ((u >> 16) & 1u)) >> 16);
}

__device__ inline float bflo(unsigned int u) { return __uint_as_float(u << 16); }
__device__ inline float bfhi(unsigned int u) { return __uint_as_float(u & 0xffff0000u); }

__global__ void f32_to_bf16_kernel(const float* __restrict__ in,
                                   unsigned short* __restrict__ out, int n4) {
    int i = blockIdx.x * blockDim.x + threadIdx.x;
    if (i < n4) {
        float4 v = *(const float4*)(in + (size_t)i * 4);
        ushort4 o;
        o.x = f2bf(v.x); o.y = f2bf(v.y); o.z = f2bf(v.z); o.w = f2bf(v.w);
        *(ushort4*)(out + (size_t)i * 4) = o;
    }
}

// ---------------- mean aggregation (r24/r27 2-chain form, 61us known good) ---

__device__ inline void addbf8(float* a, uint4 v) {
    a[0] += bflo(v.x); a[1] += bfhi(v.x);
    a[2] += bflo(v.y); a[3] += bfhi(v.y);
    a[4] += bflo(v.z); a[5] += bfhi(v.z);
    a[6] += bflo(v.w); a[7] += bfhi(v.w);
}

template <int D>
__global__ __launch_bounds__(256) void aggregate_bf16_kernel(
    const unsigned short* __restrict__ hb, const int* __restrict__ offs,
    const int* __restrict__ csr, const float* __restrict__ invd,
    unsigned short* __restrict__ meanb, int nN)
{
    constexpr int LPR = D / 8;
    constexpr int G = 64 / LPR;
    int wid = blockIdx.x * 4 + (threadIdx.x >> 6);
    int lane = threadIdx.x & 63;
    if (wid >= nN) return;
    int o0 = offs[wid], o1 = offs[wid + 1];
    const int p = lane / LPR;
    const int col = (lane % LPR) * 8;

    float a0[8] = {0.f, 0.f, 0.f, 0.f, 0.f, 0.f, 0.f, 0.f};
    float a1[8] = {0.f, 0.f, 0.f, 0.f, 0.f, 0.f, 0.f, 0.f};
    int j = o0;
    for (; j + 2 * G <= o1; j += 2 * G) {
        int s0 = csr[j + p];
        int s1 = csr[j + G + p];
        uint4 v0 = *(const uint4*)(hb + (size_t)s0 * D + col);
        uint4 v1 = *(const uint4*)(hb + (size_t)s1 * D + col);
        addbf8(a0, v0);
        addbf8(a1, v1);
    }
    if (j + G <= o1) {
        int s0 = csr[j + p];
        uint4 v0 = *(const uint4*)(hb + (size_t)s0 * D + col);
        addbf8(a0, v0);
        j += G;
    }
    if (j < o1 && p < o1 - j) {
        int s1 = csr[j + p];
        uint4 v1 = *(const uint4*)(hb + (size_t)s1 * D + col);
        addbf8(a1, v1);
    }
#pragma unroll
    for (int q = 0; q < 8; q++) a0[q] += a1[q];

#pragma unroll
    for (int m = LPR; m < 64; m <<= 1) {
#pragma unroll
        for (int q = 0; q < 8; q++) a0[q] += __shfl_xor(a0[q], m);
    }

    if (lane < LPR) {
        float iv = invd[wid];
        uint4 o;
        o.x = (unsigned)f2bf(a0[0] * iv) | ((unsigned)f2bf(a0[1] * iv) << 16);
        o.y = (unsigned)f2bf(a0[2] * iv) | ((unsigned)f2bf(a0[3] * iv) << 16);
        o.z = (unsigned)f2bf(a0[4] * iv) | ((unsigned)f2bf(a0[5] * iv) << 16);
        o.w = (unsigned)f2bf(a0[6] * iv) | ((unsigned)f2bf(a0[7] * iv) << 16);
        *(uint4*)(meanb + (size_t)wid * D + col) = o;
    }
}

// ---------------- aggregate + finish: out = relu(mean_agg(p) + bias + q) -----

template <int D, bool F32OUT>
__global__ __launch_bounds__(256) void agg_finish_kernel(
    const unsigned short* __restrict__ pb, const unsigned short* __restrict__ qb,
    const float* __restrict__ bias, const int* __restrict__ offs,
    const int* __restrict__ csr, const float* __restrict__ invd,
    unsigned short* __restrict__ outb, float* __restrict__ outf, int nN)
{
    constexpr int LPR = D / 8;
    constexpr int G = 64 / LPR;
    int wid = blockIdx.x * 4 + (threadIdx.x >> 6);
    int lane = threadIdx.x & 63;
    if (wid >= nN) return;
    int o0 = offs[wid], o1 = offs[wid + 1];
    const int p = lane / LPR;
    const int col = (lane % LPR) * 8;

    float a0[8] = {0.f, 0.f, 0.f, 0.f, 0.f, 0.f, 0.f, 0.f};
    float a1[8] = {0.f, 0.f, 0.f, 0.f, 0.f, 0.f, 0.f, 0.f};
    int j = o0;
    for (; j + 2 * G <= o1; j += 2 * G) {
        int s0 = csr[j + p];
        int s1 = csr[j + G + p];
        uint4 v0 = *(const uint4*)(pb + (size_t)s0 * D + col);
        uint4 v1 = *(const uint4*)(pb + (size_t)s1 * D + col);
        addbf8(a0, v0);
        addbf8(a1, v1);
    }
    if (j + G <= o1) {
        int s0 = csr[j + p];
        uint4 v0 = *(const uint4*)(pb + (size_t)s0 * D + col);
        addbf8(a0, v0);
        j += G;
    }
    if (j < o1 && p < o1 - j) {
        int s1 = csr[j + p];
        uint4 v1 = *(const uint4*)(pb + (size_t)s1 * D + col);
        addbf8(a1, v1);
    }
#pragma unroll
    for (int q = 0; q < 8; q++) a0[q] += a1[q];

#pragma unroll
    for (int m = LPR; m < 64; m <<= 1) {
#pragma unroll
        for (int q = 0; q < 8; q++) a0[q] += __shfl_xor(a0[q], m);
    }

    if (lane < LPR) {
        float iv = invd[wid];
        uint4 qv = *(const uint4*)(qb + (size_t)wid * D + col);
        float qf[8];
        qf[0] = bflo(qv.x); qf[1] = bfhi(qv.x);
        qf[2] = bflo(qv.y); qf[3] = bfhi(qv.y);
        qf[4] = bflo(qv.z); qf[5] = bfhi(qv.z);
        qf[6] = bflo(qv.w); qf[7] = bfhi(qv.w);
        float r[8];
#pragma unroll
        for (int q = 0; q < 8; q++)
            r[q] = fmaxf(a0[q] * iv + qf[q] + bias[col + q], 0.f);
        if (F32OUT) {
            float* dst = outf + (size_t)wid * D + col;
            *(float4*)(dst)     = make_float4(r[0], r[1], r[2], r[3]);
            *(float4*)(dst + 4) = make_float4(r[4], r[5], r[6], r[7]);
        } else {
            uint4 o;
            o.x = (unsigned)f2bf(r[0]) | ((unsigned)f2bf(r[1]) << 16);
            o.y = (unsigned)f2bf(r[2]) | ((unsigned)f2bf(r[3]) << 16);
            o.z = (unsigned)f2bf(r[4]) | ((unsigned)f2bf(r[5]) << 16);
            o.w = (unsigned)f2bf(r[6]) | ((unsigned)f2bf(r[7]) << 16);
            *(uint4*)(outb + (size_t)wid * D + col) = o;
        }
    }
}

// ---------------- MFMA GEMMs (layouts verified r22, absmax 1.95e-3) ----------

typedef short short8 __attribute__((ext_vector_type(8)));
typedef short short4v __attribute__((ext_vector_type(4)));
typedef float f32x4 __attribute__((ext_vector_type(4)));

__global__ void swizzle_w_kernel(const float* __restrict__ W,
                                 unsigned short* __restrict__ Ws,
                                 int K, int M) {
    int t = blockIdx.x * blockDim.x + threadIdx.x;
    int KB = K >> 5;
    int total = (M >> 4) * KB * 64;
    if (t >= total) return;
    int l = t & 63;
    int kbc = t >> 6;
    int kb = kbc % KB;
    int c = kbc / KB;
    int km = kb * 32 + ((l >> 4) << 2);
    int m = (c << 4) + (l & 15);
    unsigned short o[8];
#pragma unroll
    for (int j = 0; j < 8; j++) {
        int k = km + (j >> 2) * 16 + (j & 3);
        o[j] = f2bf(W[(size_t)k * M + m]);
    }
    *(uint4*)(Ws + (size_t)t * 8) = *(uint4*)o;
}

// dual-input fused GEMM (layer 1): out = relu(A1@w1 + A2@w2 + bias)
template <int K, int M>
__global__ __launch_bounds__(512) void gemm_mfma(
    const unsigned short* __restrict__ A1, const unsigned short* __restrict__ A2,
    const unsigned short* __restrict__ w1s, const unsigned short* __restrict__ w2s,
    const float* __restrict__ bias, float* __restrict__ out,
    unsigned short* __restrict__ outb, int nN)
{
    constexpr int KB = K / 32;
    constexpr int CB = M / 16;
    const int l = threadIdx.x & 63;
    const int wv = threadIdx.x >> 6;
    const int rowbase = blockIdx.x * 128 + wv * 16;
    if (rowbase >= nN) return;
    const int arow = rowbase + (l & 15);
    const int ksub = (l >> 4) << 2;

    f32x4 acc[CB];
#pragma unroll
    for (int c = 0; c < CB; c++) acc[c] = (f32x4){0.f, 0.f, 0.f, 0.f};

    const unsigned short* a1p = A1 + (size_t)arow * K + ksub;
    const unsigned short* a2p = A2 + (size_t)arow * K + ksub;

#pragma unroll
    for (int kb = 0; kb < KB; kb++) {
        short4v l1 = *(const short4v*)(a1p + kb * 32);
        short4v h1 = *(const short4v*)(a1p + kb * 32 + 16);
        short4v l2 = *(const short4v*)(a2p + kb * 32);
        short4v h2 = *(const short4v*)(a2p + kb * 32 + 16);
        short8 a1 = {l1[0], l1[1], l1[2], l1[3], h1[0], h1[1], h1[2], h1[3]};
        short8 a2 = {l2[0], l2[1], l2[2], l2[3], h2[0], h2[1], h2[2], h2[3]};
#pragma unroll
        for (int c = 0; c < CB; c++) {
            short8 b1 = *(const short8*)(w1s + ((size_t)(c * KB + kb) * 64 + l) * 8);
            acc[c] = __builtin_amdgcn_mfma_f32_16x16x32_bf16(a1, b1, acc[c], 0, 0, 0);
            short8 b2 = *(const short8*)(w2s + ((size_t)(c * KB + kb) * 64 + l) * 8);
            acc[c] = __builtin_amdgcn_mfma_f32_16x16x32_bf16(a2, b2, acc[c], 0, 0, 0);
        }
    }

    const int orow = rowbase + ((l >> 4) << 2);
#pragma unroll
    for (int c = 0; c < CB; c++) {
        int col = (c << 4) + (l & 15);
        float bv = bias[col];
#pragma unroll
        for (int r = 0; r < 4; r++) {
            float v = fmaxf(acc[c][r] + bv, 0.f);
            size_t idx = (size_t)(orow + r) * M + col;
            if (out) out[idx] = v;
            if (outb) outb[idx] = f2bf(v);
        }
    }
}

// split-output GEMM (layers 2-3): pb = A@w1 (raw), qb = A@w2 (raw); one A stream
template <int K, int M>
__global__ __launch_bounds__(512) void gemm_mfma_split(
    const unsigned short* __restrict__ A,
    const unsigned short* __restrict__ w1s, const unsigned short* __restrict__ w2s,
    unsigned short* __restrict__ pb, unsigned short* __restrict__ qb, int nN)
{
    constexpr int KB = K / 32;
    constexpr int CB = M / 16;
    const int l = threadIdx.x & 63;
    const int wv = threadIdx.x >> 6;
    const int rowbase = blockIdx.x * 128 + wv * 16;
    if (rowbase >= nN) return;
    const int arow = rowbase + (l & 15);
    const int ksub = (l >> 4) << 2;

    f32x4 accp[CB], accq[CB];
#pragma unroll
    for (int c = 0; c < CB; c++) {
        accp[c] = (f32x4){0.f, 0.f, 0.f, 0.f};
        accq[c] = (f32x4){0.f, 0.f, 0.f, 0.f};
    }

    const unsigned short* ap = A + (size_t)arow * K + ksub;

#pragma unroll
    for (int kb = 0; kb < KB; kb++) {
        short4v lo = *(const short4v*)(ap + kb * 32);
        short4v hi = *(const short4v*)(ap + kb * 32 + 16);
        short8 a = {lo[0], lo[1], lo[2], lo[3], hi[0], hi[1], hi[2], hi[3]};
#pragma unroll
        for (int c = 0; c < CB; c++) {
            short8 b1 = *(const short8*)(w1s + ((size_t)(c * KB + kb) * 64 + l) * 8);
            accp[c] = __builtin_amdgcn_mfma_f32_16x16x32_bf16(a, b1, accp[c], 0, 0, 0);
            short8 b2 = *(const short8*)(w2s + ((size_t)(c * KB + kb) * 64 + l) * 8);
            accq[c] = __builtin_amdgcn_mfma_f32_16x16x32_bf16(a, b2, accq[c], 0, 0, 0);
        }
    }

    const int orow = rowbase + ((l >> 4) << 2);
#pragma unroll
    for (int c = 0; c < CB; c++) {
        int col = (c << 4) + (l & 15);
#pragma unroll
        for (int r = 0; r < 4; r++) {
            size_t idx = (size_t)(orow + r) * M + col;
            pb[idx] = f2bf(accp[c][r]);
            qb[idx] = f2bf(accq[c][r]);
        }
    }
}

// ---------------- classifier: [N,32] @ [32,2] + bc ----------------

__global__ void classifier_kernel(const float* __restrict__ h,
                                  const float* __restrict__ wc,
                                  const float* __restrict__ bc,
                                  float* __restrict__ out, int nN) {
    int n = blockIdx.x * blockDim.x + threadIdx.x;
    if (n >= nN) return;
    float a0 = bc[0], a1 = bc[1];
    const float* row = h + (size_t)n * 32;
#pragma unroll
    for (int k = 0; k < 32; k++) {
        float v = row[k];
        a0 = fmaf(v, wc[k * 2 + 0], a0);
        a1 = fmaf(v, wc[k * 2 + 1], a1);
    }
    out[n * 2 + 0] = a0;
    out[n * 2 + 1] = a1;
}

// ---------------- launch ----------------

extern "C" void kernel_launch(void* const* d_in, const int* in_sizes, int n_in,
                              void* d_out, int out_size, void* d_ws, size_t ws_size,
                              hipStream_t stream) {
    const float* x   = (const float*)d_in[0];
    const int*   ei  = (const int*)d_in[1];   // [2,E] int32
    const float* w1l = (const float*)d_in[2];
    const float* b1l = (const float*)d_in[3];
    const float* w1r = (const float*)d_in[4];
    const float* w2l = (const float*)d_in[5];
    const float* b2l = (const float*)d_in[6];
    const float* w2r = (const float*)d_in[7];
    const float* w3l = (const float*)d_in[8];
    const float* b3l = (const float*)d_in[9];
    const float* w3r = (const float*)d_in[10];
    const float* wc  = (const float*)d_in[11];
    const float* bc  = (const float*)d_in[12];
    float* out = (float*)d_out;

    const int N = in_sizes[0] / 128;
    const int E = in_sizes[1] / 2;
    const int NBq = (N + 511) >> 9;           // 512-node buckets (196)

    char* p = (char*)d_ws;
    auto alloc = [&](size_t bytes) {
        char* r = p;
        p += (bytes + 511) & ~(size_t)511;
        return r;
    };
    int*   offs   = (int*)  alloc(((size_t)N + 1) * 4);
    float* invd   = (float*)alloc((size_t)N * 4);
    int*   bcnt   = (int*)  alloc(256 * 4);
    int*   bbase  = (int*)  alloc(257 * 4);
    int*   bcur   = (int*)  alloc(256 * 4);
    uint2* ebuf   = (uint2*)alloc((size_t)E * 8);
    int*   csr    = (int*)  alloc((size_t)E * 4);
    float* h3     = (float*)alloc((size_t)N * 32 * 4);
    unsigned short* xb    = (unsigned short*)alloc((size_t)N * 128 * 2);
    unsigned short* h1b   = (unsigned short*)alloc((size_t)N * 128 * 2);
    unsigned short* h2b   = (unsigned short*)alloc((size_t)N * 64 * 2);
    unsigned short* meanb = (unsigned short*)alloc((size_t)N * 128 * 2);
    unsigned short* p2b   = (unsigned short*)alloc((size_t)N * 64 * 2);
    unsigned short* q2b   = (unsigned short*)alloc((size_t)N * 64 * 2);
    unsigned short* p3b   = (unsigned short*)alloc((size_t)N * 32 * 2);
    unsigned short* q3b   = (unsigned short*)alloc((size_t)N * 32 * 2);
    unsigned short* w1ls  = (unsigned short*)alloc(128 * 128 * 2);
    unsigned short* w1rs  = (unsigned short*)alloc(128 * 128 * 2);
    unsigned short* w2ls  = (unsigned short*)alloc(128 * 64 * 2);
    unsigned short* w2rs  = (unsigned short*)alloc(128 * 64 * 2);
    unsigned short* w3ls  = (unsigned short*)alloc(64 * 32 * 2);
    unsigned short* w3rs  = (unsigned short*)alloc(64 * 32 * 2);

    hipMemsetAsync(bcnt, 0, 256 * 4, stream);

    int eb4 = (E + EBLK - 1) / EBLK;
    bucket_hist_kernel<<<eb4, 256, 0, stream>>>(ei, bcnt, E);
    bucket_scan_kernel<<<1, 256, 0, stream>>>(bcnt, bbase, bcur, NBq, E);
    bin_scatter_kernel<<<eb4, 256, 0, stream>>>(ei, bcur, ebuf, E);
    bucket_fill_kernel<<<NBq, 512, 0, stream>>>(ebuf, bbase, offs, invd, csr, N, E);

    int n4 = N * 128 / 4;
    f32_to_bf16_kernel<<<(n4 + 255) / 256, 256, 0, stream>>>(x, xb, n4);

    // weight swizzle (tiny)
    swizzle_w_kernel<<<(128 * 128 / 8 + 255) / 256, 256, 0, stream>>>(w1l, w1ls, 128, 128);
    swizzle_w_kernel<<<(128 * 128 / 8 + 255) / 256, 256, 0, stream>>>(w1r, w1rs, 128, 128);
    swizzle_w_kernel<<<(128 * 64 / 8 + 255) / 256, 256, 0, stream>>>(w2l, w2ls, 128, 64);
    swizzle_w_kernel<<<(128 * 64 / 8 + 255) / 256, 256, 0, stream>>>(w2r, w2rs, 128, 64);
    swizzle_w_kernel<<<(64 * 32 / 8 + 255) / 256, 256, 0, stream>>>(w3l, w3ls, 64, 32);
    swizzle_w_kernel<<<(64 * 32 / 8 + 255) / 256, 256, 0, stream>>>(w3r, w3rs, 64, 32);

    int ab = (N + 3) / 4;
    int gm = (N + 127) / 128;     // 128 rows per MFMA block

    // layer 1 (widths equal -> classic order)
    aggregate_bf16_kernel<128><<<ab, 256, 0, stream>>>(xb, offs, csr, invd, meanb, N);
    gemm_mfma<128, 128><<<gm, 512, 0, stream>>>(meanb, xb, w1ls, w1rs, b1l, nullptr, h1b, N);

    // layer 2 (aggregate AFTER lin_l: gather 64-wide instead of 128-wide)
    gemm_mfma_split<128, 64><<<gm, 512, 0, stream>>>(h1b, w2ls, w2rs, p2b, q2b, N);
    agg_finish_kernel<64, false><<<ab, 256, 0, stream>>>(p2b, q2b, b2l, offs, csr, invd, h2b, nullptr, N);

    // layer 3 (gather 32-wide instead of 64-wide)
    gemm_mfma_split<64, 32><<<gm, 512, 0, stream>>>(h2b, w3ls, w3rs, p3b, q3b, N);
    agg_finish_kernel<32, true><<<ab, 256, 0, stream>>>(p3b, q3b, b3l, offs, csr, invd, nullptr, h3, N);

    classifier_kernel<<<(N + 255) / 256, 256, 0, stream>>>(h3, wc, bc, out, N);
}